// Round 8
// baseline (300.848 us; speedup 1.0000x reference)
//
#include <hip/hip_runtime.h>

#define CHN 16
#define HID 128
#define NB 32
#define NH 128
#define NW 128
#define NPIX (NB*NH*NW)      // 524288
#define TPB 256
#define YSTR 56              // Ys row stride (shorts): 112B, 16B-aligned, 2-way banks

typedef __attribute__((ext_vector_type(8))) short bf16x8;
typedef __attribute__((ext_vector_type(4))) float f32x4;
typedef __attribute__((ext_vector_type(4))) int i32x4;

// JAX threefry2x32 (20 rounds). Verified vs Random123 test vectors.
__host__ __device__ inline void threefry2x32(unsigned k0, unsigned k1,
                                             unsigned x0, unsigned x1,
                                             unsigned &o0, unsigned &o1) {
  unsigned ks2 = 0x1BD11BDAu ^ k0 ^ k1;
  unsigned v0 = x0 + k0, v1 = x1 + k1;
#define TF_R(r) { v0 += v1; v1 = (v1 << (r)) | (v1 >> (32-(r))); v1 ^= v0; }
  TF_R(13) TF_R(15) TF_R(26) TF_R(6)
  v0 += k1;  v1 += ks2 + 1u;
  TF_R(17) TF_R(29) TF_R(16) TF_R(24)
  v0 += ks2; v1 += k0 + 2u;
  TF_R(13) TF_R(15) TF_R(26) TF_R(6)
  v0 += k0;  v1 += k1 + 3u;
  TF_R(17) TF_R(29) TF_R(16) TF_R(24)
  v0 += k1;  v1 += ks2 + 4u;
  TF_R(13) TF_R(15) TF_R(26) TF_R(6)
  v0 += ks2; v1 += k0 + 5u;
#undef TF_R
  o0 = v0; o1 = v1;
}

// RNE f32->bf16 via compiler __bf16 (lowers to v_cvt_pk_bf16_f32; RNE like validated path)
__device__ inline unsigned short f2bf(float f) {
  return __builtin_bit_cast(unsigned short, (__bf16)f);
}
__device__ inline unsigned pk2(float lo, float hi) {
  return (unsigned)f2bf(lo) | ((unsigned)f2bf(hi) << 16);
}
__device__ inline bf16x8 cvt8(float4 a, float4 b) {
  i32x4 r;
  r[0] = (int)pk2(a.x, a.y); r[1] = (int)pk2(a.z, a.w);
  r[2] = (int)pk2(b.x, b.y); r[3] = (int)pk2(b.z, b.w);
  return __builtin_bit_cast(bf16x8, r);
}

// Kernel A: perceive -> H^T = W0*Y^T (relu, bias folded at k=48, W0 from L1/global)
// -> dx^T = W1*H^T (permlane transpose) -> x_mid = x + dx*fire. No barrier.
// LDS = Ys(28672) + fireS(1024) = 29696 B -> 5 blocks/CU.
__global__ __launch_bounds__(TPB, 5) void ca_step_a(
    const float* __restrict__ xin,
    const float* __restrict__ W0g,
    const float* __restrict__ b0g,
    const float* __restrict__ W1g,
    float* __restrict__ xmid,
    float* __restrict__ alphaOut,
    unsigned char* __restrict__ preLife,
    unsigned sk0, unsigned sk1)
{
  __shared__ __align__(16) short Ys[256 * YSTR];  // [q][48 used of 56] bf16
  __shared__ float fireS[256];

  const int tid = threadIdx.x;
  const int l = tid & 63, w = tid >> 6;
  const int lc = l & 15, lg = l >> 4;

  // ---- perceive (lane <-> pixel 1:1) ----
  const int pBase = blockIdx.x * TPB;
  const int p = pBase + tid;
  const int j = p & (NW - 1);
  const int i0 = (p >> 7) & (NH - 1);

  float yc[CHN], y1[CHN], y2[CHN];
#pragma unroll
  for (int c = 0; c < CHN; ++c) { yc[c] = 0.f; y1[c] = 0.f; y2[c] = 0.f; }
  float amax = -1e30f;

#pragma unroll
  for (int dh = 0; dh < 3; ++dh) {
#pragma unroll
    for (int dw = 0; dw < 3; ++dw) {
      const int ii = i0 + dh - 1, jj = j + dw - 1;
      if ((unsigned)ii < NH && (unsigned)jj < NW) {
        const float* src = xin + ((size_t)p + (size_t)(dh - 1) * NW + (dw - 1)) * CHN;
        float v[CHN];
        *(float4*)(v)      = *(const float4*)(src);
        *(float4*)(v + 4)  = *(const float4*)(src + 4);
        *(float4*)(v + 8)  = *(const float4*)(src + 8);
        *(float4*)(v + 12) = *(const float4*)(src + 12);
        amax = fmaxf(amax, v[3]);
        const float gh = (dh == 0) ? -1.f : ((dh == 2) ? 1.f : 0.f);
        const float sh = (dh == 1) ? 2.f : 1.f;
        const float gw = (dw == 0) ? -1.f : ((dw == 2) ? 1.f : 0.f);
        const float sw = (dw == 1) ? 2.f : 1.f;
        const float g1 = gh * sw * 0.125f;
        const float g2 = sh * gw * 0.125f;
        if (dh == 1 && dw == 1) {
#pragma unroll
          for (int c = 0; c < CHN; ++c) yc[c] = v[c];
        }
        if (g1 != 0.f) {
#pragma unroll
          for (int c = 0; c < CHN; ++c) y1[c] = fmaf(g1, v[c], y1[c]);
        }
        if (g2 != 0.f) {
#pragma unroll
          for (int c = 0; c < CHN; ++c) y2[c] = fmaf(g2, v[c], y2[c]);
        }
      }
    }
  }

  preLife[p] = (amax > 0.1f) ? (unsigned char)1 : (unsigned char)0;
  {
    unsigned b1_, b2_;
    threefry2x32(sk0, sk1, 0u, (unsigned)p, b1_, b2_);   // partitionable: bits = v0^v1
    fireS[tid] = ((b1_ ^ b2_) & 0x80000000u) ? 0.f : 1.f;
  }

  // pack Y row: [yc | y1 | y2] = 48 bf16 = 3 x 16B (wave-local LDS, in-order DS)
  {
    i32x4 u0, u1, u2;
    u0[0] = (int)pk2(yc[0], yc[1]);   u0[1] = (int)pk2(yc[2], yc[3]);
    u0[2] = (int)pk2(yc[4], yc[5]);   u0[3] = (int)pk2(yc[6], yc[7]);
    u1[0] = (int)pk2(yc[8], yc[9]);   u1[1] = (int)pk2(yc[10], yc[11]);
    u1[2] = (int)pk2(yc[12], yc[13]); u1[3] = (int)pk2(yc[14], yc[15]);
    *(i32x4*)&Ys[tid * YSTR]     = u0;
    *(i32x4*)&Ys[tid * YSTR + 8] = u1;
    u0[0] = (int)pk2(y1[0], y1[1]);   u0[1] = (int)pk2(y1[2], y1[3]);
    u0[2] = (int)pk2(y1[4], y1[5]);   u0[3] = (int)pk2(y1[6], y1[7]);
    u1[0] = (int)pk2(y1[8], y1[9]);   u1[1] = (int)pk2(y1[10], y1[11]);
    u1[2] = (int)pk2(y1[12], y1[13]); u1[3] = (int)pk2(y1[14], y1[15]);
    u2[0] = (int)pk2(y2[0], y2[1]);   u2[1] = (int)pk2(y2[2], y2[3]);
    u2[2] = (int)pk2(y2[4], y2[5]);   u2[3] = (int)pk2(y2[6], y2[7]);
    *(i32x4*)&Ys[tid * YSTR + 16] = u0;
    *(i32x4*)&Ys[tid * YSTR + 24] = u1;
    *(i32x4*)&Ys[tid * YSTR + 32] = u2;
    u2[0] = (int)pk2(y2[8], y2[9]);   u2[1] = (int)pk2(y2[10], y2[11]);
    u2[2] = (int)pk2(y2[12], y2[13]); u2[3] = (int)pk2(y2[14], y2[15]);
    *(i32x4*)&Ys[tid * YSTR + 40] = u2;
  }

  // ---- W1 A-fragments from global (row c=lc, k=kt*32+lg*8..+8) ----
  bf16x8 W1f[4];
#pragma unroll
  for (int kt = 0; kt < 4; ++kt) {
    const float* src = &W1g[lc * HID + kt * 32 + (lg << 3)];
    W1f[kt] = cvt8(*(const float4*)(src), *(const float4*)(src + 4));
  }

  const bf16x8 zero8 = {};
  bf16x8 one8 = {};
  one8[0] = (short)0x3F80;            // bf16 1.0 at k=48 -> picks up bias col

  // Y B-fragments for all 4 m-tiles (wave-local; no barrier needed)
  bf16x8 Yf[4][2];
#pragma unroll
  for (int m = 0; m < 4; ++m) {
    const int q = ((w << 6) + (m << 4) + lc) * YSTR;
    Yf[m][0] = *(const bf16x8*)&Ys[q + (lg << 3)];
    Yf[m][1] = (lg < 2) ? *(const bf16x8*)&Ys[q + 32 + (lg << 3)]
                        : ((lg == 2) ? one8 : zero8);
  }

  f32x4 dxacc[4];
#pragma unroll
  for (int m = 0; m < 4; ++m) dxacc[m] = (f32x4){0.f, 0.f, 0.f, 0.f};

  const int c1off = (lg < 2) ? (32 + (lg << 3)) : 0;   // clamped addr for lg>=2

#pragma unroll
  for (int kt_o = 0; kt_o < 4; ++kt_o) {
    // W0 fragments for both 16-row tiles of this kt_o, straight from global (L1-hot)
    bf16x8 Wf0[2], Wf1[2];
#pragma unroll
    for (int th = 0; th < 2; ++th) {
      const int row = (((kt_o << 1) + th) << 4) + lc;
      const float* wp = W0g + row * 48;
      const bf16x8 w0 = cvt8(*(const float4*)(wp + (lg << 3)),
                             *(const float4*)(wp + (lg << 3) + 4));
      const float4 wc = *(const float4*)(wp + c1off);
      const float4 wd = *(const float4*)(wp + c1off + 4);
      const float bb = b0g[row];
      bf16x8 bias8 = zero8;
      bias8[0] = (short)f2bf(bb);
      Wf0[th] = w0;
      Wf1[th] = (lg < 2) ? cvt8(wc, wd) : ((lg == 2) ? bias8 : zero8);
    }
#pragma unroll
    for (int m = 0; m < 4; ++m) {
      f32x4 a0 = __builtin_amdgcn_mfma_f32_16x16x32_bf16(
          Wf0[0], Yf[m][0], (f32x4){0.f, 0.f, 0.f, 0.f}, 0, 0, 0);
      a0 = __builtin_amdgcn_mfma_f32_16x16x32_bf16(Wf1[0], Yf[m][1], a0, 0, 0, 0);
      f32x4 a1 = __builtin_amdgcn_mfma_f32_16x16x32_bf16(
          Wf0[1], Yf[m][0], (f32x4){0.f, 0.f, 0.f, 0.f}, 0, 0, 0);
      a1 = __builtin_amdgcn_mfma_f32_16x16x32_bf16(Wf1[1], Yf[m][1], a1, 0, 0, 0);
      // relu + pack
      unsigned xa = pk2(fmaxf(a0[0], 0.f), fmaxf(a0[1], 0.f));
      unsigned xb = pk2(fmaxf(a0[2], 0.f), fmaxf(a0[3], 0.f));
      unsigned ya = pk2(fmaxf(a1[0], 0.f), fmaxf(a1[1], 0.f));
      unsigned yb = pk2(fmaxf(a1[2], 0.f), fmaxf(a1[3], 0.f));
      // lg-group transpose (VALU): [a0..a3],[b0..b3] -> [a0,a2,b0,b2],[a1,a3,b1,b3]
      asm("v_permlane32_swap_b32 %0, %1" : "+v"(xa), "+v"(ya));
      asm("v_permlane32_swap_b32 %0, %1" : "+v"(xb), "+v"(yb));
      asm("v_permlane16_swap_b32 %0, %1" : "+v"(xa), "+v"(ya));
      asm("v_permlane16_swap_b32 %0, %1" : "+v"(xb), "+v"(yb));
      i32x4 bfr;
      bfr[0] = (int)xa;   // k lg*8+0,1
      bfr[1] = (int)xb;   // k lg*8+2,3
      bfr[2] = (int)ya;   // k lg*8+4,5
      bfr[3] = (int)yb;   // k lg*8+6,7
      dxacc[m] = __builtin_amdgcn_mfma_f32_16x16x32_bf16(
          W1f[kt_o], __builtin_bit_cast(bf16x8, bfr), dxacc[m], 0, 0, 0);
    }
  }

  // ---- epilogue: dx^T C-layout (row c=lg*4+r, col px=m*16+lc) -> float4/lane ----
#pragma unroll
  for (int m = 0; m < 4; ++m) {
    const int q = (w << 6) + (m << 4) + lc;
    const int pp = pBase + q;
    const float f = fireS[q];
    const float* src = &xin[(size_t)pp * CHN + (lg << 2)];
    float4 xc = *(const float4*)src;
    float4 xm;
    xm.x = fmaf(dxacc[m][0], f, xc.x);
    xm.y = fmaf(dxacc[m][1], f, xc.y);
    xm.z = fmaf(dxacc[m][2], f, xc.z);
    xm.w = fmaf(dxacc[m][3], f, xc.w);
    *(float4*)&xmid[(size_t)pp * CHN + (lg << 2)] = xm;
    if (lg == 0) alphaOut[pp] = xm.w;   // channel 3
  }
}

// Kernel B: post_life = 3x3 maxpool(alpha) > 0.1; x = x_mid * (pre & post)
__global__ __launch_bounds__(TPB) void ca_step_b(
    const float* __restrict__ xmid,
    const float* __restrict__ alphaIn,
    const unsigned char* __restrict__ preLife,
    float* __restrict__ xout)
{
  const int p = blockIdx.x * TPB + threadIdx.x;
  const int j = p & (NW - 1);
  const int i = (p >> 7) & (NH - 1);
  float pmax = -1e30f;
#pragma unroll
  for (int dh = 0; dh < 3; ++dh) {
#pragma unroll
    for (int dw = 0; dw < 3; ++dw) {
      const int ii = i + dh - 1, jj = j + dw - 1;
      if ((unsigned)ii < NH && (unsigned)jj < NW)
        pmax = fmaxf(pmax, alphaIn[p + (dh - 1) * NW + (dw - 1)]);
    }
  }
  const float m = ((pmax > 0.1f) && (preLife[p] != 0)) ? 1.f : 0.f;
  const float* src = xmid + (size_t)p * CHN;
  float4 a = *(const float4*)(src);
  float4 b = *(const float4*)(src + 4);
  float4 c = *(const float4*)(src + 8);
  float4 d = *(const float4*)(src + 12);
  a.x *= m; a.y *= m; a.z *= m; a.w *= m;
  b.x *= m; b.y *= m; b.z *= m; b.w *= m;
  c.x *= m; c.y *= m; c.z *= m; c.w *= m;
  d.x *= m; d.y *= m; d.z *= m; d.w *= m;
  float* dst = xout + (size_t)p * CHN;
  *(float4*)(dst)      = a;
  *(float4*)(dst + 4)  = b;
  *(float4*)(dst + 8)  = c;
  *(float4*)(dst + 12) = d;
}

extern "C" void kernel_launch(void* const* d_in, const int* in_sizes, int n_in,
                              void* d_out, int out_size, void* d_ws, size_t ws_size,
                              hipStream_t stream) {
  const float* x  = (const float*)d_in[0];
  const float* W0 = (const float*)d_in[1];
  const float* b0 = (const float*)d_in[2];
  const float* W1 = (const float*)d_in[3];
  float* out = (float*)d_out;

  char* ws = (char*)d_ws;
  float* X = (float*)ws;                                        // NPIX*16 f32
  float* alphaB = (float*)(ws + (size_t)NPIX * CHN * 4);        // NPIX f32
  unsigned char* pl = (unsigned char*)(ws + (size_t)NPIX * CHN * 4 + (size_t)NPIX * 4);

  const dim3 grid(NPIX / TPB), block(TPB);
  const int STEPS = 4;
  for (int s = 0; s < STEPS; ++s) {
    unsigned k0, k1;
    threefry2x32(0u, 42u, 0u, (unsigned)s, k0, k1);   // fold_in(key(42), s)
    const float* src = (s == 0) ? x : X;
    ca_step_a<<<grid, block, 0, stream>>>(src, W0, b0, W1, out, alphaB, pl, k0, k1);
    float* dst = (s == STEPS - 1) ? out : X;
    ca_step_b<<<grid, block, 0, stream>>>(out, alphaB, pl, dst);
  }
}

// Round 9
// 263.810 us; speedup vs baseline: 1.1404x; 1.1404x over previous
//
#include <hip/hip_runtime.h>

#define CHN 16
#define HID 128
#define NB 32
#define NH 128
#define NW 128
#define NPIX (NB*NH*NW)      // 524288
#define TPB 256
#define YSTR 56              // Ys row stride (shorts): 112B, 16B-aligned, 2-way banks

typedef __attribute__((ext_vector_type(8))) short bf16x8;
typedef __attribute__((ext_vector_type(4))) float f32x4;
typedef __attribute__((ext_vector_type(4))) int i32x4;

// JAX threefry2x32 (20 rounds). Verified vs Random123 test vectors.
__host__ __device__ inline void threefry2x32(unsigned k0, unsigned k1,
                                             unsigned x0, unsigned x1,
                                             unsigned &o0, unsigned &o1) {
  unsigned ks2 = 0x1BD11BDAu ^ k0 ^ k1;
  unsigned v0 = x0 + k0, v1 = x1 + k1;
#define TF_R(r) { v0 += v1; v1 = (v1 << (r)) | (v1 >> (32-(r))); v1 ^= v0; }
  TF_R(13) TF_R(15) TF_R(26) TF_R(6)
  v0 += k1;  v1 += ks2 + 1u;
  TF_R(17) TF_R(29) TF_R(16) TF_R(24)
  v0 += ks2; v1 += k0 + 2u;
  TF_R(13) TF_R(15) TF_R(26) TF_R(6)
  v0 += k0;  v1 += k1 + 3u;
  TF_R(17) TF_R(29) TF_R(16) TF_R(24)
  v0 += k1;  v1 += ks2 + 4u;
  TF_R(13) TF_R(15) TF_R(26) TF_R(6)
  v0 += ks2; v1 += k0 + 5u;
#undef TF_R
  o0 = v0; o1 = v1;
}

// RNE f32->bf16 via compiler __bf16 (lowers to v_cvt_pk_bf16_f32 pairs)
__device__ inline unsigned short f2bf(float f) {
  return __builtin_bit_cast(unsigned short, (__bf16)f);
}
__device__ inline unsigned pk2(float lo, float hi) {
  return (unsigned)f2bf(lo) | ((unsigned)f2bf(hi) << 16);
}
__device__ inline bf16x8 cvt8(float4 a, float4 b) {
  i32x4 r;
  r[0] = (int)pk2(a.x, a.y); r[1] = (int)pk2(a.z, a.w);
  r[2] = (int)pk2(b.x, b.y); r[3] = (int)pk2(b.z, b.w);
  return __builtin_bit_cast(bf16x8, r);
}

// Kernel A: perceive -> H^T = W0*Y^T (relu, bias folded at k=48, W0 from L1/global)
// -> dx^T = W1*H^T (permlane transpose) -> x_mid = x + dx*fire. No barrier.
// LDS = Ys(28672) + fireS(1024) = 29696 B. launch_bounds(,4): 128-VGPR cap, NO spills
// (,5 capped at ~102 and spilled ~76B/thread to scratch -> +70MB HBM, r8 regression).
__global__ __launch_bounds__(TPB, 4) void ca_step_a(
    const float* __restrict__ xin,
    const float* __restrict__ W0g,
    const float* __restrict__ b0g,
    const float* __restrict__ W1g,
    float* __restrict__ xmid,
    float* __restrict__ alphaOut,
    unsigned char* __restrict__ preLife,
    unsigned sk0, unsigned sk1)
{
  __shared__ __align__(16) short Ys[256 * YSTR];  // [q][48 used of 56] bf16
  __shared__ float fireS[256];

  const int tid = threadIdx.x;
  const int l = tid & 63, w = tid >> 6;
  const int lc = l & 15, lg = l >> 4;

  // ---- perceive (lane <-> pixel 1:1) ----
  const int pBase = blockIdx.x * TPB;
  const int p = pBase + tid;
  const int j = p & (NW - 1);
  const int i0 = (p >> 7) & (NH - 1);

  float yc[CHN], y1[CHN], y2[CHN];
#pragma unroll
  for (int c = 0; c < CHN; ++c) { yc[c] = 0.f; y1[c] = 0.f; y2[c] = 0.f; }
  float amax = -1e30f;

#pragma unroll
  for (int dh = 0; dh < 3; ++dh) {
#pragma unroll
    for (int dw = 0; dw < 3; ++dw) {
      const int ii = i0 + dh - 1, jj = j + dw - 1;
      if ((unsigned)ii < NH && (unsigned)jj < NW) {
        const float* src = xin + ((size_t)p + (size_t)(dh - 1) * NW + (dw - 1)) * CHN;
        float v[CHN];
        *(float4*)(v)      = *(const float4*)(src);
        *(float4*)(v + 4)  = *(const float4*)(src + 4);
        *(float4*)(v + 8)  = *(const float4*)(src + 8);
        *(float4*)(v + 12) = *(const float4*)(src + 12);
        amax = fmaxf(amax, v[3]);
        const float gh = (dh == 0) ? -1.f : ((dh == 2) ? 1.f : 0.f);
        const float sh = (dh == 1) ? 2.f : 1.f;
        const float gw = (dw == 0) ? -1.f : ((dw == 2) ? 1.f : 0.f);
        const float sw = (dw == 1) ? 2.f : 1.f;
        const float g1 = gh * sw * 0.125f;
        const float g2 = sh * gw * 0.125f;
        if (dh == 1 && dw == 1) {
#pragma unroll
          for (int c = 0; c < CHN; ++c) yc[c] = v[c];
        }
        if (g1 != 0.f) {
#pragma unroll
          for (int c = 0; c < CHN; ++c) y1[c] = fmaf(g1, v[c], y1[c]);
        }
        if (g2 != 0.f) {
#pragma unroll
          for (int c = 0; c < CHN; ++c) y2[c] = fmaf(g2, v[c], y2[c]);
        }
      }
    }
  }

  preLife[p] = (amax > 0.1f) ? (unsigned char)1 : (unsigned char)0;
  {
    unsigned b1_, b2_;
    threefry2x32(sk0, sk1, 0u, (unsigned)p, b1_, b2_);   // partitionable: bits = v0^v1
    fireS[tid] = ((b1_ ^ b2_) & 0x80000000u) ? 0.f : 1.f;
  }

  // pack Y row: [yc | y1 | y2] = 48 bf16 = 3 x 16B (wave-local LDS, in-order DS)
  {
    i32x4 u0, u1, u2;
    u0[0] = (int)pk2(yc[0], yc[1]);   u0[1] = (int)pk2(yc[2], yc[3]);
    u0[2] = (int)pk2(yc[4], yc[5]);   u0[3] = (int)pk2(yc[6], yc[7]);
    u1[0] = (int)pk2(yc[8], yc[9]);   u1[1] = (int)pk2(yc[10], yc[11]);
    u1[2] = (int)pk2(yc[12], yc[13]); u1[3] = (int)pk2(yc[14], yc[15]);
    *(i32x4*)&Ys[tid * YSTR]     = u0;
    *(i32x4*)&Ys[tid * YSTR + 8] = u1;
    u0[0] = (int)pk2(y1[0], y1[1]);   u0[1] = (int)pk2(y1[2], y1[3]);
    u0[2] = (int)pk2(y1[4], y1[5]);   u0[3] = (int)pk2(y1[6], y1[7]);
    u1[0] = (int)pk2(y1[8], y1[9]);   u1[1] = (int)pk2(y1[10], y1[11]);
    u1[2] = (int)pk2(y1[12], y1[13]); u1[3] = (int)pk2(y1[14], y1[15]);
    u2[0] = (int)pk2(y2[0], y2[1]);   u2[1] = (int)pk2(y2[2], y2[3]);
    u2[2] = (int)pk2(y2[4], y2[5]);   u2[3] = (int)pk2(y2[6], y2[7]);
    *(i32x4*)&Ys[tid * YSTR + 16] = u0;
    *(i32x4*)&Ys[tid * YSTR + 24] = u1;
    *(i32x4*)&Ys[tid * YSTR + 32] = u2;
    u2[0] = (int)pk2(y2[8], y2[9]);   u2[1] = (int)pk2(y2[10], y2[11]);
    u2[2] = (int)pk2(y2[12], y2[13]); u2[3] = (int)pk2(y2[14], y2[15]);
    *(i32x4*)&Ys[tid * YSTR + 40] = u2;
  }

  // ---- W1 A-fragments from global (row c=lc, k=kt*32+lg*8..+8) ----
  bf16x8 W1f[4];
#pragma unroll
  for (int kt = 0; kt < 4; ++kt) {
    const float* src = &W1g[lc * HID + kt * 32 + (lg << 3)];
    W1f[kt] = cvt8(*(const float4*)(src), *(const float4*)(src + 4));
  }

  const bf16x8 zero8 = {};
  bf16x8 one8 = {};
  one8[0] = (short)0x3F80;            // bf16 1.0 at k=48 -> picks up bias col

  // Y B-fragments for all 4 m-tiles (wave-local; no barrier needed)
  bf16x8 Yf[4][2];
#pragma unroll
  for (int m = 0; m < 4; ++m) {
    const int q = ((w << 6) + (m << 4) + lc) * YSTR;
    Yf[m][0] = *(const bf16x8*)&Ys[q + (lg << 3)];
    Yf[m][1] = (lg < 2) ? *(const bf16x8*)&Ys[q + 32 + (lg << 3)]
                        : ((lg == 2) ? one8 : zero8);
  }

  f32x4 dxacc[4];
#pragma unroll
  for (int m = 0; m < 4; ++m) dxacc[m] = (f32x4){0.f, 0.f, 0.f, 0.f};

  const int c1off = (lg < 2) ? (32 + (lg << 3)) : 0;   // clamped addr for lg>=2

#pragma unroll
  for (int kt_o = 0; kt_o < 4; ++kt_o) {
    // W0 fragments for both 16-row tiles of this kt_o, straight from global (L1-hot)
    bf16x8 Wf0[2], Wf1[2];
#pragma unroll
    for (int th = 0; th < 2; ++th) {
      const int row = (((kt_o << 1) + th) << 4) + lc;
      const float* wp = W0g + row * 48;
      const bf16x8 w0 = cvt8(*(const float4*)(wp + (lg << 3)),
                             *(const float4*)(wp + (lg << 3) + 4));
      const float4 wc = *(const float4*)(wp + c1off);
      const float4 wd = *(const float4*)(wp + c1off + 4);
      const float bb = b0g[row];
      bf16x8 bias8 = zero8;
      bias8[0] = (short)f2bf(bb);
      Wf0[th] = w0;
      Wf1[th] = (lg < 2) ? cvt8(wc, wd) : ((lg == 2) ? bias8 : zero8);
    }
#pragma unroll
    for (int m = 0; m < 4; ++m) {
      f32x4 a0 = __builtin_amdgcn_mfma_f32_16x16x32_bf16(
          Wf0[0], Yf[m][0], (f32x4){0.f, 0.f, 0.f, 0.f}, 0, 0, 0);
      a0 = __builtin_amdgcn_mfma_f32_16x16x32_bf16(Wf1[0], Yf[m][1], a0, 0, 0, 0);
      f32x4 a1 = __builtin_amdgcn_mfma_f32_16x16x32_bf16(
          Wf0[1], Yf[m][0], (f32x4){0.f, 0.f, 0.f, 0.f}, 0, 0, 0);
      a1 = __builtin_amdgcn_mfma_f32_16x16x32_bf16(Wf1[1], Yf[m][1], a1, 0, 0, 0);
      // relu + pack
      unsigned xa = pk2(fmaxf(a0[0], 0.f), fmaxf(a0[1], 0.f));
      unsigned xb = pk2(fmaxf(a0[2], 0.f), fmaxf(a0[3], 0.f));
      unsigned ya = pk2(fmaxf(a1[0], 0.f), fmaxf(a1[1], 0.f));
      unsigned yb = pk2(fmaxf(a1[2], 0.f), fmaxf(a1[3], 0.f));
      // lg-group transpose (VALU): [a0..a3],[b0..b3] -> [a0,a2,b0,b2],[a1,a3,b1,b3]
      asm("v_permlane32_swap_b32 %0, %1" : "+v"(xa), "+v"(ya));
      asm("v_permlane32_swap_b32 %0, %1" : "+v"(xb), "+v"(yb));
      asm("v_permlane16_swap_b32 %0, %1" : "+v"(xa), "+v"(ya));
      asm("v_permlane16_swap_b32 %0, %1" : "+v"(xb), "+v"(yb));
      i32x4 bfr;
      bfr[0] = (int)xa;   // k lg*8+0,1
      bfr[1] = (int)xb;   // k lg*8+2,3
      bfr[2] = (int)ya;   // k lg*8+4,5
      bfr[3] = (int)yb;   // k lg*8+6,7
      dxacc[m] = __builtin_amdgcn_mfma_f32_16x16x32_bf16(
          W1f[kt_o], __builtin_bit_cast(bf16x8, bfr), dxacc[m], 0, 0, 0);
    }
  }

  // ---- epilogue: dx^T C-layout (row c=lg*4+r, col px=m*16+lc) -> float4/lane ----
#pragma unroll
  for (int m = 0; m < 4; ++m) {
    const int q = (w << 6) + (m << 4) + lc;
    const int pp = pBase + q;
    const float f = fireS[q];
    const float* src = &xin[(size_t)pp * CHN + (lg << 2)];
    float4 xc = *(const float4*)src;
    float4 xm;
    xm.x = fmaf(dxacc[m][0], f, xc.x);
    xm.y = fmaf(dxacc[m][1], f, xc.y);
    xm.z = fmaf(dxacc[m][2], f, xc.z);
    xm.w = fmaf(dxacc[m][3], f, xc.w);
    *(float4*)&xmid[(size_t)pp * CHN + (lg << 2)] = xm;
    if (lg == 0) alphaOut[pp] = xm.w;   // channel 3
  }
}

// Kernel B: post_life = 3x3 maxpool(alpha) > 0.1; x = x_mid * (pre & post)
__global__ __launch_bounds__(TPB) void ca_step_b(
    const float* __restrict__ xmid,
    const float* __restrict__ alphaIn,
    const unsigned char* __restrict__ preLife,
    float* __restrict__ xout)
{
  const int p = blockIdx.x * TPB + threadIdx.x;
  const int j = p & (NW - 1);
  const int i = (p >> 7) & (NH - 1);
  float pmax = -1e30f;
#pragma unroll
  for (int dh = 0; dh < 3; ++dh) {
#pragma unroll
    for (int dw = 0; dw < 3; ++dw) {
      const int ii = i + dh - 1, jj = j + dw - 1;
      if ((unsigned)ii < NH && (unsigned)jj < NW)
        pmax = fmaxf(pmax, alphaIn[p + (dh - 1) * NW + (dw - 1)]);
    }
  }
  const float m = ((pmax > 0.1f) && (preLife[p] != 0)) ? 1.f : 0.f;
  const float* src = xmid + (size_t)p * CHN;
  float4 a = *(const float4*)(src);
  float4 b = *(const float4*)(src + 4);
  float4 c = *(const float4*)(src + 8);
  float4 d = *(const float4*)(src + 12);
  a.x *= m; a.y *= m; a.z *= m; a.w *= m;
  b.x *= m; b.y *= m; b.z *= m; b.w *= m;
  c.x *= m; c.y *= m; c.z *= m; c.w *= m;
  d.x *= m; d.y *= m; d.z *= m; d.w *= m;
  float* dst = xout + (size_t)p * CHN;
  *(float4*)(dst)      = a;
  *(float4*)(dst + 4)  = b;
  *(float4*)(dst + 8)  = c;
  *(float4*)(dst + 12) = d;
}

extern "C" void kernel_launch(void* const* d_in, const int* in_sizes, int n_in,
                              void* d_out, int out_size, void* d_ws, size_t ws_size,
                              hipStream_t stream) {
  const float* x  = (const float*)d_in[0];
  const float* W0 = (const float*)d_in[1];
  const float* b0 = (const float*)d_in[2];
  const float* W1 = (const float*)d_in[3];
  float* out = (float*)d_out;

  char* ws = (char*)d_ws;
  float* X = (float*)ws;                                        // NPIX*16 f32
  float* alphaB = (float*)(ws + (size_t)NPIX * CHN * 4);        // NPIX f32
  unsigned char* pl = (unsigned char*)(ws + (size_t)NPIX * CHN * 4 + (size_t)NPIX * 4);

  const dim3 grid(NPIX / TPB), block(TPB);
  const int STEPS = 4;
  for (int s = 0; s < STEPS; ++s) {
    unsigned k0, k1;
    threefry2x32(0u, 42u, 0u, (unsigned)s, k0, k1);   // fold_in(key(42), s)
    const float* src = (s == 0) ? x : X;
    ca_step_a<<<grid, block, 0, stream>>>(src, W0, b0, W1, out, alphaB, pl, k0, k1);
    float* dst = (s == STEPS - 1) ? out : X;
    ca_step_b<<<grid, block, 0, stream>>>(out, alphaB, pl, dst);
  }
}

// Round 11
// 220.654 us; speedup vs baseline: 1.3634x; 1.1956x over previous
//
#include <hip/hip_runtime.h>

#define CHN 16
#define HID 128
#define NB 32
#define NH 128
#define NW 128
#define NPIX (NB*NH*NW)      // 524288
#define TPB 256
#define YSTR 48              // Ys row stride (shorts): 96B, 16B-aligned
#define WSTR 56              // W0s row stride: cols 0..47=W0, 48=b0, 49..55=0

typedef __attribute__((ext_vector_type(8))) short bf16x8;
typedef __attribute__((ext_vector_type(4))) float f32x4;
typedef __attribute__((ext_vector_type(4))) int i32x4;

// JAX threefry2x32 (20 rounds). Verified vs Random123 test vectors.
__host__ __device__ inline void threefry2x32(unsigned k0, unsigned k1,
                                             unsigned x0, unsigned x1,
                                             unsigned &o0, unsigned &o1) {
  unsigned ks2 = 0x1BD11BDAu ^ k0 ^ k1;
  unsigned v0 = x0 + k0, v1 = x1 + k1;
#define TF_R(r) { v0 += v1; v1 = (v1 << (r)) | (v1 >> (32-(r))); v1 ^= v0; }
  TF_R(13) TF_R(15) TF_R(26) TF_R(6)
  v0 += k1;  v1 += ks2 + 1u;
  TF_R(17) TF_R(29) TF_R(16) TF_R(24)
  v0 += ks2; v1 += k0 + 2u;
  TF_R(13) TF_R(15) TF_R(26) TF_R(6)
  v0 += k0;  v1 += k1 + 3u;
  TF_R(17) TF_R(29) TF_R(16) TF_R(24)
  v0 += k1;  v1 += ks2 + 4u;
  TF_R(13) TF_R(15) TF_R(26) TF_R(6)
  v0 += ks2; v1 += k0 + 5u;
#undef TF_R
  o0 = v0; o1 = v1;
}

// RNE f32->bf16 via compiler __bf16 (lowers to v_cvt_pk_bf16_f32 pairs)
__device__ inline unsigned short f2bf(float f) {
  return __builtin_bit_cast(unsigned short, (__bf16)f);
}
__device__ inline unsigned pk2(float lo, float hi) {
  return (unsigned)f2bf(lo) | ((unsigned)f2bf(hi) << 16);
}
__device__ inline bf16x8 cvt8(float4 a, float4 b) {
  i32x4 r;
  r[0] = (int)pk2(a.x, a.y); r[1] = (int)pk2(a.z, a.w);
  r[2] = (int)pk2(b.x, b.y); r[3] = (int)pk2(b.z, b.w);
  return __builtin_bit_cast(bf16x8, r);
}

// Kernel A: perceive -> H^T = W0*Y^T (relu, bias folded at k=48, W0 staged in LDS)
// -> dx^T = W1*H^T (permlane transpose) -> x_mid = x + dx*fire.
// fire via __ballot (no LDS); epilogue xin prefetched before MFMA loop (T14).
// LDS = W0s(14336) + Ys(24576) = 38912 B -> 4 blocks/CU.
__global__ __launch_bounds__(TPB, 4) void ca_step_a(
    const float* __restrict__ xin,
    const float* __restrict__ W0g,
    const float* __restrict__ b0g,
    const float* __restrict__ W1g,
    float* __restrict__ xmid,
    float* __restrict__ alphaOut,
    unsigned char* __restrict__ preLife,
    unsigned sk0, unsigned sk1)
{
  __shared__ __align__(16) short W0s[128 * WSTR];  // 14336 B
  __shared__ __align__(16) short Ys[256 * YSTR];   // 24576 B

  const int tid = threadIdx.x;
  const int l = tid & 63, w = tid >> 6;
  const int lc = l & 15, lg = l >> 4;

  // ---- stage W0 (f32->bf16) + bias col 48 + zero pad 49..55 ----
  {
    const int o = tid >> 1;
    if ((tid & 1) == 0) {
#pragma unroll
      for (int k = 0; k < 24; k += 2)
        *(unsigned*)&W0s[o * WSTR + k] = pk2(W0g[o * 48 + k], W0g[o * 48 + k + 1]);
    } else {
#pragma unroll
      for (int k = 24; k < 48; k += 2)
        *(unsigned*)&W0s[o * WSTR + k] = pk2(W0g[o * 48 + k], W0g[o * 48 + k + 1]);
      *(unsigned*)&W0s[o * WSTR + 48] = (unsigned)f2bf(b0g[o]);   // (b0, 0)
      *(unsigned*)&W0s[o * WSTR + 50] = 0u;
      *(unsigned*)&W0s[o * WSTR + 52] = 0u;
      *(unsigned*)&W0s[o * WSTR + 54] = 0u;
    }
  }

  // ---- perceive (lane <-> pixel 1:1) ----
  const int pBase = blockIdx.x * TPB;
  const int p = pBase + tid;
  const int j = p & (NW - 1);
  const int i0 = (p >> 7) & (NH - 1);

  float yc[CHN], y1[CHN], y2[CHN];
#pragma unroll
  for (int c = 0; c < CHN; ++c) { yc[c] = 0.f; y1[c] = 0.f; y2[c] = 0.f; }
  float amax = -1e30f;

#pragma unroll
  for (int dh = 0; dh < 3; ++dh) {
#pragma unroll
    for (int dw = 0; dw < 3; ++dw) {
      const int ii = i0 + dh - 1, jj = j + dw - 1;
      if ((unsigned)ii < NH && (unsigned)jj < NW) {
        const float* src = xin + ((size_t)p + (size_t)(dh - 1) * NW + (dw - 1)) * CHN;
        float v[CHN];
        *(float4*)(v)      = *(const float4*)(src);
        *(float4*)(v + 4)  = *(const float4*)(src + 4);
        *(float4*)(v + 8)  = *(const float4*)(src + 8);
        *(float4*)(v + 12) = *(const float4*)(src + 12);
        amax = fmaxf(amax, v[3]);
        const float gh = (dh == 0) ? -1.f : ((dh == 2) ? 1.f : 0.f);
        const float sh = (dh == 1) ? 2.f : 1.f;
        const float gw = (dw == 0) ? -1.f : ((dw == 2) ? 1.f : 0.f);
        const float sw = (dw == 1) ? 2.f : 1.f;
        const float g1 = gh * sw * 0.125f;
        const float g2 = sh * gw * 0.125f;
        if (dh == 1 && dw == 1) {
#pragma unroll
          for (int c = 0; c < CHN; ++c) yc[c] = v[c];
        }
        if (g1 != 0.f) {
#pragma unroll
          for (int c = 0; c < CHN; ++c) y1[c] = fmaf(g1, v[c], y1[c]);
        }
        if (g2 != 0.f) {
#pragma unroll
          for (int c = 0; c < CHN; ++c) y2[c] = fmaf(g2, v[c], y2[c]);
        }
      }
    }
  }

  preLife[p] = (amax > 0.1f) ? (unsigned char)1 : (unsigned char)0;
  unsigned long long fmask;
  {
    unsigned b1_, b2_;
    threefry2x32(sk0, sk1, 0u, (unsigned)p, b1_, b2_);   // partitionable: bits = v0^v1
    fmask = __ballot(((b1_ ^ b2_) & 0x80000000u) == 0u); // wave-wide fire bits
  }

  // pack Y row: [yc | y1 | y2] = 48 bf16 = 3 x 16B (wave-local LDS, in-order DS)
  {
    i32x4 u0, u1, u2;
    u0[0] = (int)pk2(yc[0], yc[1]);   u0[1] = (int)pk2(yc[2], yc[3]);
    u0[2] = (int)pk2(yc[4], yc[5]);   u0[3] = (int)pk2(yc[6], yc[7]);
    u1[0] = (int)pk2(yc[8], yc[9]);   u1[1] = (int)pk2(yc[10], yc[11]);
    u1[2] = (int)pk2(yc[12], yc[13]); u1[3] = (int)pk2(yc[14], yc[15]);
    *(i32x4*)&Ys[tid * YSTR]     = u0;
    *(i32x4*)&Ys[tid * YSTR + 8] = u1;
    u0[0] = (int)pk2(y1[0], y1[1]);   u0[1] = (int)pk2(y1[2], y1[3]);
    u0[2] = (int)pk2(y1[4], y1[5]);   u0[3] = (int)pk2(y1[6], y1[7]);
    u1[0] = (int)pk2(y1[8], y1[9]);   u1[1] = (int)pk2(y1[10], y1[11]);
    u1[2] = (int)pk2(y1[12], y1[13]); u1[3] = (int)pk2(y1[14], y1[15]);
    u2[0] = (int)pk2(y2[0], y2[1]);   u2[1] = (int)pk2(y2[2], y2[3]);
    u2[2] = (int)pk2(y2[4], y2[5]);   u2[3] = (int)pk2(y2[6], y2[7]);
    *(i32x4*)&Ys[tid * YSTR + 16] = u0;
    *(i32x4*)&Ys[tid * YSTR + 24] = u1;
    *(i32x4*)&Ys[tid * YSTR + 32] = u2;
    u2[0] = (int)pk2(y2[8], y2[9]);   u2[1] = (int)pk2(y2[10], y2[11]);
    u2[2] = (int)pk2(y2[12], y2[13]); u2[3] = (int)pk2(y2[14], y2[15]);
    *(i32x4*)&Ys[tid * YSTR + 40] = u2;
  }

  // ---- W1 A-fragments from global (row c=lc, k=kt*32+lg*8..+8) ----
  bf16x8 W1f[4];
#pragma unroll
  for (int kt = 0; kt < 4; ++kt) {
    const float* src = &W1g[lc * HID + kt * 32 + (lg << 3)];
    W1f[kt] = cvt8(*(const float4*)(src), *(const float4*)(src + 4));
  }

  __syncthreads();   // W0s visible (Ys wave-local)

  const bf16x8 zero8 = {};
  bf16x8 one8 = {};
  one8[0] = (short)0x3F80;            // bf16 1.0 at k=48 -> picks up bias col

  // Y B-fragments for all 4 m-tiles
  bf16x8 Yf[4][2];
#pragma unroll
  for (int m = 0; m < 4; ++m) {
    const int q = ((w << 6) + (m << 4) + lc) * YSTR;
    Yf[m][0] = *(const bf16x8*)&Ys[q + (lg << 3)];
    Yf[m][1] = (lg < 2) ? *(const bf16x8*)&Ys[q + 32 + (lg << 3)]
                        : ((lg == 2) ? one8 : zero8);
  }

  // T14: prefetch epilogue x reloads (L1-hot) so latency hides under MFMAs
  float4 xpre[4];
#pragma unroll
  for (int m = 0; m < 4; ++m) {
    const int pp = pBase + (w << 6) + (m << 4) + lc;
    xpre[m] = *(const float4*)&xin[(size_t)pp * CHN + (lg << 2)];
  }

  f32x4 dxacc[4];
#pragma unroll
  for (int m = 0; m < 4; ++m) dxacc[m] = (f32x4){0.f, 0.f, 0.f, 0.f};

#pragma unroll
  for (int kt_o = 0; kt_o < 4; ++kt_o) {
    // W0 fragments for both 16-row tiles of this kt_o from LDS
    bf16x8 Wf0[2], Wf1[2];
#pragma unroll
    for (int th = 0; th < 2; ++th) {
      const int row = ((((kt_o << 1) + th) << 4) + lc) * WSTR;
      Wf0[th] = *(const bf16x8*)&W0s[row + (lg << 3)];
      Wf1[th] = (lg < 3) ? *(const bf16x8*)&W0s[row + 32 + (lg << 3)] : zero8;
    }
#pragma unroll
    for (int m = 0; m < 4; ++m) {
      f32x4 a0 = __builtin_amdgcn_mfma_f32_16x16x32_bf16(
          Wf0[0], Yf[m][0], (f32x4){0.f, 0.f, 0.f, 0.f}, 0, 0, 0);
      a0 = __builtin_amdgcn_mfma_f32_16x16x32_bf16(Wf1[0], Yf[m][1], a0, 0, 0, 0);
      f32x4 a1 = __builtin_amdgcn_mfma_f32_16x16x32_bf16(
          Wf0[1], Yf[m][0], (f32x4){0.f, 0.f, 0.f, 0.f}, 0, 0, 0);
      a1 = __builtin_amdgcn_mfma_f32_16x16x32_bf16(Wf1[1], Yf[m][1], a1, 0, 0, 0);
      // relu + pack
      unsigned xa = pk2(fmaxf(a0[0], 0.f), fmaxf(a0[1], 0.f));
      unsigned xb = pk2(fmaxf(a0[2], 0.f), fmaxf(a0[3], 0.f));
      unsigned ya = pk2(fmaxf(a1[0], 0.f), fmaxf(a1[1], 0.f));
      unsigned yb = pk2(fmaxf(a1[2], 0.f), fmaxf(a1[3], 0.f));
      // lg-group transpose (VALU): [a0..a3],[b0..b3] -> [a0,a2,b0,b2],[a1,a3,b1,b3]
      asm("v_permlane32_swap_b32 %0, %1" : "+v"(xa), "+v"(ya));
      asm("v_permlane32_swap_b32 %0, %1" : "+v"(xb), "+v"(yb));
      asm("v_permlane16_swap_b32 %0, %1" : "+v"(xa), "+v"(ya));
      asm("v_permlane16_swap_b32 %0, %1" : "+v"(xb), "+v"(yb));
      i32x4 bfr;
      bfr[0] = (int)xa;   // k lg*8+0,1
      bfr[1] = (int)xb;   // k lg*8+2,3
      bfr[2] = (int)ya;   // k lg*8+4,5
      bfr[3] = (int)yb;   // k lg*8+6,7
      dxacc[m] = __builtin_amdgcn_mfma_f32_16x16x32_bf16(
          W1f[kt_o], __builtin_bit_cast(bf16x8, bfr), dxacc[m], 0, 0, 0);
    }
  }

  // ---- epilogue: dx^T C-layout (row c=lg*4+r, col px=m*16+lc) -> float4/lane ----
#pragma unroll
  for (int m = 0; m < 4; ++m) {
    const int q = (m << 4) + lc;               // lane holding pixel's fire bit
    const int pp = pBase + (w << 6) + q;
    const float f = (float)((fmask >> q) & 1ull);
    float4 xm;
    xm.x = fmaf(dxacc[m][0], f, xpre[m].x);
    xm.y = fmaf(dxacc[m][1], f, xpre[m].y);
    xm.z = fmaf(dxacc[m][2], f, xpre[m].z);
    xm.w = fmaf(dxacc[m][3], f, xpre[m].w);
    *(float4*)&xmid[(size_t)pp * CHN + (lg << 2)] = xm;
    if (lg == 0) alphaOut[pp] = xm.w;   // channel 3
  }
}

// Kernel B: post_life = 3x3 maxpool(alpha) > 0.1; x = x_mid * (pre & post)
__global__ __launch_bounds__(TPB) void ca_step_b(
    const float* __restrict__ xmid,
    const float* __restrict__ alphaIn,
    const unsigned char* __restrict__ preLife,
    float* __restrict__ xout)
{
  const int p = blockIdx.x * TPB + threadIdx.x;
  const int j = p & (NW - 1);
  const int i = (p >> 7) & (NH - 1);
  float pmax = -1e30f;
#pragma unroll
  for (int dh = 0; dh < 3; ++dh) {
#pragma unroll
    for (int dw = 0; dw < 3; ++dw) {
      const int ii = i + dh - 1, jj = j + dw - 1;
      if ((unsigned)ii < NH && (unsigned)jj < NW)
        pmax = fmaxf(pmax, alphaIn[p + (dh - 1) * NW + (dw - 1)]);
    }
  }
  const float m = ((pmax > 0.1f) && (preLife[p] != 0)) ? 1.f : 0.f;
  const float* src = xmid + (size_t)p * CHN;
  float4 a = *(const float4*)(src);
  float4 b = *(const float4*)(src + 4);
  float4 c = *(const float4*)(src + 8);
  float4 d = *(const float4*)(src + 12);
  a.x *= m; a.y *= m; a.z *= m; a.w *= m;
  b.x *= m; b.y *= m; b.z *= m; b.w *= m;
  c.x *= m; c.y *= m; c.z *= m; c.w *= m;
  d.x *= m; d.y *= m; d.z *= m; d.w *= m;
  float* dst = xout + (size_t)p * CHN;
  *(float4*)(dst)      = a;
  *(float4*)(dst + 4)  = b;
  *(float4*)(dst + 8)  = c;
  *(float4*)(dst + 12) = d;
}

extern "C" void kernel_launch(void* const* d_in, const int* in_sizes, int n_in,
                              void* d_out, int out_size, void* d_ws, size_t ws_size,
                              hipStream_t stream) {
  const float* x  = (const float*)d_in[0];
  const float* W0 = (const float*)d_in[1];
  const float* b0 = (const float*)d_in[2];
  const float* W1 = (const float*)d_in[3];
  float* out = (float*)d_out;

  char* ws = (char*)d_ws;
  float* X = (float*)ws;                                        // NPIX*16 f32
  float* alphaB = (float*)(ws + (size_t)NPIX * CHN * 4);        // NPIX f32
  unsigned char* pl = (unsigned char*)(ws + (size_t)NPIX * CHN * 4 + (size_t)NPIX * 4);

  const dim3 grid(NPIX / TPB), block(TPB);
  const int STEPS = 4;
  for (int s = 0; s < STEPS; ++s) {
    unsigned k0, k1;
    threefry2x32(0u, 42u, 0u, (unsigned)s, k0, k1);   // fold_in(key(42), s)
    const float* src = (s == 0) ? x : X;
    ca_step_a<<<grid, block, 0, stream>>>(src, W0, b0, W1, out, alphaB, pl, k0, k1);
    float* dst = (s == STEPS - 1) ? out : X;
    ca_step_b<<<grid, block, 0, stream>>>(out, alphaB, pl, dst);
  }
}